// Round 6
// baseline (856.310 us; speedup 1.0000x reference)
//
#include <hip/hip_runtime.h>
#include <hip/hip_bf16.h>
#include <math.h>

#define BB 16
#define SS 2048
#define DD 512
#define NDOCS 200000
#define TOPK 5
#define EPSN 1e-12f
#define NEG_INF (-3.0e38f)

#define NBLK3 768
#define NW (NBLK3 * 4)          // 3072 scanning waves
#define NTILE (NDOCS / 8)       // 25000 8-doc tiles

typedef short s16x8 __attribute__((ext_vector_type(8)));
typedef float f32x4 __attribute__((ext_vector_type(4)));

__device__ __forceinline__ short f2bf(float f) {
    __bf16 b = (__bf16)f;
    short s;
    __builtin_memcpy(&s, &b, 2);
    return s;
}

__device__ __forceinline__ void gload_lds16(const void* g, void* l) {
    __builtin_amdgcn_global_load_lds(
        (const __attribute__((address_space(1))) void*)g,
        (__attribute__((address_space(3))) void*)l, 16, 0, 0);
}

// ---------------- K1: partial mean pool: partial[32][16][512] ----------------
__global__ __launch_bounds__(128) void k1_mean_partial(
    const float* __restrict__ hs, float* __restrict__ partial) {
    int b = blockIdx.y, sc = blockIdx.x;
    int t = threadIdx.x;
    const float4* src = (const float4*)(hs + (size_t)(b * SS + sc * 64) * DD);
    float4 acc = {0.f, 0.f, 0.f, 0.f};
    for (int s = 0; s < 64; ++s) {
        float4 v = src[(size_t)s * 128 + t];
        acc.x += v.x; acc.y += v.y; acc.z += v.z; acc.w += v.w;
    }
    ((float4*)partial)[(size_t)(sc * BB + b) * 128 + t] = acc;
}

// ---------------- K1b: reduce partials -> mean[16][512] ----------------
__global__ __launch_bounds__(128) void k1b_mean_reduce(
    const float* __restrict__ partial, float* __restrict__ mean) {
    int b = blockIdx.y, jc = blockIdx.x;
    int j = jc * 128 + threadIdx.x;
    float s = 0.f;
    for (int c = 0; c < 32; ++c) s += partial[(size_t)(c * BB + b) * DD + j];
    mean[(size_t)b * DD + j] = s * (1.0f / 2048.0f);
}

// ---------------- K2a: qtmp[b][j] = mean[b] . Wq[j] + bq[j] ----------------
__global__ __launch_bounds__(256) void k2a_q_gemv(
    const float* __restrict__ mean, const float* __restrict__ Wq,
    const float* __restrict__ bq, float* __restrict__ qtmp) {
    int b = blockIdx.y, jc = blockIdx.x;
    int t = threadIdx.x;
    int r = t >> 4, c = t & 15;
    int row = jc * 16 + r;
    const float4* wr = (const float4*)(Wq + (size_t)row * DD);
    const float4* mv = (const float4*)(mean + (size_t)b * DD);
    float acc = 0.f;
#pragma unroll
    for (int it = 0; it < 8; ++it) {
        int k4 = c + it * 16;
        float4 w = wr[k4], m = mv[k4];
        acc = fmaf(w.x, m.x, acc); acc = fmaf(w.y, m.y, acc);
        acc = fmaf(w.z, m.z, acc); acc = fmaf(w.w, m.w, acc);
    }
#pragma unroll
    for (int m = 1; m < 16; m <<= 1) acc += __shfl_xor(acc, m);
    if (c == 0) qtmp[(size_t)b * DD + row] = acc + bq[row];
}

// ---------------- K2b: l2-normalize qtmp -> qv ----------------
__global__ __launch_bounds__(256) void k2b_q_norm(
    const float* __restrict__ qtmp, float* __restrict__ qv) {
    int b = blockIdx.x, t = threadIdx.x;
    __shared__ float red[4];
    float a0 = qtmp[(size_t)b * DD + t];
    float a1 = qtmp[(size_t)b * DD + t + 256];
    float ss = a0 * a0 + a1 * a1;
#pragma unroll
    for (int m = 1; m < 64; m <<= 1) ss += __shfl_xor(ss, m);
    if ((t & 63) == 0) red[t >> 6] = ss;
    __syncthreads();
    float inv = 1.0f / fmaxf(sqrtf(red[0] + red[1] + red[2] + red[3]), EPSN);
    qv[(size_t)b * DD + t] = a0 * inv;
    qv[(size_t)b * DD + t + 256] = a1 * inv;
}

// ---------------- K2c: build swizzled f32 q table qphys[8][16][4][4][4] -----
// logical (k,b): j=k>>6, dgrp=(k>>2)&15, e=k&3, g=b>>2, bi=b&3
// phys idx = j*1024 + dgrp*64 + (e^((dgrp>>2)&3))*16 + ((g^(dgrp&3))<<2) + bi
__global__ __launch_bounds__(512) void k2c_qsplit(
    const float* __restrict__ qv, float* __restrict__ qphys) {
    int k = threadIdx.x;
    int j = k >> 6, dgrp = (k >> 2) & 15, e = k & 3;
    int edg = (dgrp >> 2) & 3, gdg = dgrp & 3;
    int base = j * 1024 + dgrp * 64 + ((e ^ edg) << 4);
#pragma unroll
    for (int b = 0; b < BB; ++b) {
        int g = b >> 2, bi = b & 3;
        qphys[base + (((g ^ gdg)) << 2) + bi] = qv[(size_t)b * DD + k];
    }
}

// ---------------- K3: barrier-free fp32 streaming scan (8-doc tiles) --------
// 768 blocks x 256 thr. Wave owns 8-doc tiles. q table (32KB) in LDS.
// lane: rgrp=l>>4 (row subgroup), dgrp=l&15 (dim subgroup).
// Register budget deliberate: acc 32 + cur/nxt 16 + topk/qoffs/misc ~45 < 128.
__global__ __launch_bounds__(256, 4) void k3_scores(
    const float* __restrict__ docs, const float* __restrict__ qphys,
    float* __restrict__ cand_s, int* __restrict__ cand_i) {
    __shared__ float qS[8192];    // 32KB swizzled q table

    int t = threadIdx.x;
    int w = t >> 6, lane = t & 63;
    int rgrp = lane >> 4, dgrp = lane & 15;

    // stage q table once (linear copy; swizzle pre-baked by K2c)
#pragma unroll
    for (int jj = 0; jj < 8; ++jj) {
        int u = ((w * 8 + jj) << 6) + lane;          // float4 unit
        gload_lds16(qphys + (size_t)u * 4, (void*)&qS[(w * 8 + jj) * 256]);
    }
    __syncthreads();

    // lane-constant swizzled q offsets (floats) for logical (e,g)
    int edg = (dgrp >> 2) & 3, gdg = dgrp & 3;
    int qoffs[4][4];
#pragma unroll
    for (int e = 0; e < 4; ++e)
#pragma unroll
        for (int g = 0; g < 4; ++g)
            qoffs[e][g] = dgrp * 64 + ((e ^ edg) << 4) + ((g ^ gdg) << 2);

    int gw = blockIdx.x * 4 + w;

    float lv[TOPK]; int li[TOPK];
#pragma unroll
    for (int r = 0; r < TOPK; ++r) { lv[r] = NEG_INF; li[r] = 0x7fffffff; }

    auto ins = [&](float s, int di) {
        if (s > lv[4] || (s == lv[4] && di < li[4])) {
            lv[4] = s; li[4] = di;
#pragma unroll
            for (int k = 4; k > 0; --k) {
                if (lv[k] > lv[k - 1] || (lv[k] == lv[k - 1] && li[k] < li[k - 1])) {
                    float tv = lv[k]; lv[k] = lv[k - 1]; lv[k - 1] = tv;
                    int   ti = li[k]; li[k] = li[k - 1]; li[k - 1] = ti;
                }
            }
        }
    };

    // doc loads: slot rr reads row tile*8 + 4*rr + rgrp at dims j*64 + dgrp*4
    // (per instruction: 4 rgrp-rows x 256B contiguous segments)
    auto loadrr = [&](long tt, int j, f32x4* dst) {
        const float* p = docs + ((size_t)tt * 8 + rgrp) * DD + j * 64 + dgrp * 4;
        dst[0] = *(const f32x4*)(p);
        dst[1] = *(const f32x4*)(p + 2048);
    };

    int p0 = dgrp & 1, p1 = (dgrp >> 1) & 1, p2 = (dgrp >> 2) & 1, p3 = (dgrp >> 3) & 1;

    f32x4 cur[2], nxt[2];
    if (gw < NTILE) loadrr(gw, 0, cur);

    for (long tt = gw; tt < NTILE; tt += NW) {
        long ttn = (tt + NW < NTILE) ? tt + NW : tt;

        f32x4 acc[2][4];
        float nrm[2];
#pragma unroll
        for (int rr = 0; rr < 2; ++rr) {
            nrm[rr] = 0.f;
#pragma unroll
            for (int g = 0; g < 4; ++g) acc[rr][g] = (f32x4){0.f, 0.f, 0.f, 0.f};
        }

#pragma unroll
        for (int j = 0; j < 8; ++j) {
            if (j < 7) loadrr(tt, j + 1, nxt);
            else       loadrr(ttn, 0, nxt);
            const float* qj = qS + j * 1024;
#pragma unroll
            for (int e = 0; e < 4; ++e) {
#pragma unroll
                for (int rr = 0; rr < 2; ++rr)
                    nrm[rr] = fmaf(cur[rr][e], cur[rr][e], nrm[rr]);
#pragma unroll
                for (int g = 0; g < 4; ++g) {
                    f32x4 qq = *(const f32x4*)(qj + qoffs[e][g]);
#pragma unroll
                    for (int rr = 0; rr < 2; ++rr) {
                        float ee = cur[rr][e];
                        acc[rr][g][0] = fmaf(ee, qq[0], acc[rr][g][0]);
                        acc[rr][g][1] = fmaf(ee, qq[1], acc[rr][g][1]);
                        acc[rr][g][2] = fmaf(ee, qq[2], acc[rr][g][2]);
                        acc[rr][g][3] = fmaf(ee, qq[3], acc[rr][g][3]);
                    }
                }
            }
#pragma unroll
            for (int rr = 0; rr < 2; ++rr) cur[rr] = nxt[rr];
        }

        // ---- decimated butterfly reduce over dgrp: lane ends with batch b=dgrp
        float n1r[2][8];
#pragma unroll
        for (int rr = 0; rr < 2; ++rr)
#pragma unroll
            for (int bh = 0; bh < 8; ++bh) {
                int g = bh >> 1, c0 = 2 * (bh & 1);
                float tx   = p0 ? acc[rr][g][c0]     : acc[rr][g][c0 + 1];
                float mine = p0 ? acc[rr][g][c0 + 1] : acc[rr][g][c0];
                n1r[rr][bh] = mine + __shfl_xor(tx, 1);
            }
        float n2r[2][4];
#pragma unroll
        for (int rr = 0; rr < 2; ++rr)
#pragma unroll
            for (int bq = 0; bq < 4; ++bq) {
                float tx   = p1 ? n1r[rr][2 * bq]     : n1r[rr][2 * bq + 1];
                float mine = p1 ? n1r[rr][2 * bq + 1] : n1r[rr][2 * bq];
                n2r[rr][bq] = mine + __shfl_xor(tx, 2);
            }
        float n3r[2][2];
#pragma unroll
        for (int rr = 0; rr < 2; ++rr)
#pragma unroll
            for (int bo = 0; bo < 2; ++bo) {
                float tx   = p2 ? n2r[rr][2 * bo]     : n2r[rr][2 * bo + 1];
                float mine = p2 ? n2r[rr][2 * bo + 1] : n2r[rr][2 * bo];
                n3r[rr][bo] = mine + __shfl_xor(tx, 4);
            }
        float red[2];
#pragma unroll
        for (int rr = 0; rr < 2; ++rr) {
            float tx   = p3 ? n3r[rr][0] : n3r[rr][1];
            float mine = p3 ? n3r[rr][1] : n3r[rr][0];
            red[rr] = mine + __shfl_xor(tx, 8);
        }
        // norms: full butterfly over dgrp bits (same for all batches)
#pragma unroll
        for (int m = 1; m < 16; m <<= 1)
#pragma unroll
            for (int rr = 0; rr < 2; ++rr) nrm[rr] += __shfl_xor(nrm[rr], m);

#pragma unroll
        for (int rr = 0; rr < 2; ++rr) {
            float sc = red[rr] / fmaxf(sqrtf(nrm[rr]), EPSN);
            ins(sc, (int)(tt * 8 + 4 * rr + rgrp));
        }
    }

    // merge top-5 across the 4 rgrp groups (same dgrp = same batch)
#pragma unroll
    for (int step = 16; step <= 32; step <<= 1) {
        float ov[TOPK]; int oi[TOPK];
#pragma unroll
        for (int r = 0; r < TOPK; ++r) {
            ov[r] = __shfl_xor(lv[r], step);
            oi[r] = __shfl_xor(li[r], step);
        }
#pragma unroll
        for (int r = 0; r < TOPK; ++r) ins(ov[r], oi[r]);
    }

    if (rgrp == 0) {
#pragma unroll
        for (int r = 0; r < TOPK; ++r) {
            cand_s[((long)gw * BB + dgrp) * TOPK + r] = lv[r];
            cand_i[((long)gw * BB + dgrp) * TOPK + r] = li[r];
        }
    }
}

// ---------------- K4a: merge top-5, softmax, context, outputs ----------------
__global__ __launch_bounds__(256) void k4a_topk_ctx(
    const float* __restrict__ docs, const float* __restrict__ cand_s,
    const int* __restrict__ cand_i, float* __restrict__ ctx,
    float* __restrict__ outp) {
    int b = blockIdx.x, t = threadIdx.x;
    __shared__ float sv[256];
    __shared__ int   si[256];
    __shared__ float topv[TOPK];
    __shared__ int   topi[TOPK];
    __shared__ float red[4];
    __shared__ float nrm5[TOPK];
    __shared__ float wts[TOPK];

    float lv[TOPK]; int li[TOPK];
#pragma unroll
    for (int r = 0; r < TOPK; ++r) { lv[r] = NEG_INF; li[r] = 0x7fffffff; }

    for (int j = t; j < NW * TOPK; j += 256) {
        int blk = j / TOPK, r = j - blk * TOPK;
        float s = cand_s[(long)blk * (BB * TOPK) + b * TOPK + r];
        int  di = cand_i[(long)blk * (BB * TOPK) + b * TOPK + r];
        if (s > lv[TOPK - 1] || (s == lv[TOPK - 1] && di < li[TOPK - 1])) {
            lv[TOPK - 1] = s; li[TOPK - 1] = di;
#pragma unroll
            for (int k = TOPK - 1; k > 0; --k) {
                if (lv[k] > lv[k - 1] || (lv[k] == lv[k - 1] && li[k] < li[k - 1])) {
                    float tv = lv[k]; lv[k] = lv[k - 1]; lv[k - 1] = tv;
                    int   ti = li[k]; li[k] = li[k - 1]; li[k - 1] = ti;
                }
            }
        }
    }

    int p = 0;
    for (int r = 0; r < TOPK; ++r) {
        float hv = (p < TOPK) ? lv[p] : NEG_INF;
        int   hi = (p < TOPK) ? li[p] : 0x7fffffff;
        sv[t] = hv; si[t] = hi;
        __syncthreads();
        for (int off = 128; off > 0; off >>= 1) {
            if (t < off) {
                float ov = sv[t + off]; int oi = si[t + off];
                if (ov > sv[t] || (ov == sv[t] && oi < si[t])) { sv[t] = ov; si[t] = oi; }
            }
            __syncthreads();
        }
        if (t == 0) { topv[r] = sv[0]; topi[r] = si[0]; }
        __syncthreads();
        if (hv == topv[r] && hi == topi[r]) ++p;
        __syncthreads();
    }

    for (int r = 0; r < TOPK; ++r) {
        const float* dr = docs + (size_t)topi[r] * DD;
        float s2 = dr[t] * dr[t] + dr[t + 256] * dr[t + 256];
#pragma unroll
        for (int m = 1; m < 64; m <<= 1) s2 += __shfl_xor(s2, m);
        if ((t & 63) == 0) red[t >> 6] = s2;
        __syncthreads();
        if (t == 0) nrm5[r] = sqrtf(red[0] + red[1] + red[2] + red[3]);
        __syncthreads();
    }

    if (t == 0) {
        float m = topv[0];
        float e[TOPK], s = 0.f;
#pragma unroll
        for (int r = 0; r < TOPK; ++r) { e[r] = expf(topv[r] - m); s += e[r]; }
#pragma unroll
        for (int r = 0; r < TOPK; ++r) wts[r] = e[r] / s;
    }
    __syncthreads();

    for (int j = t; j < DD; j += 256) {
        float c = 0.f;
#pragma unroll
        for (int r = 0; r < TOPK; ++r)
            c += wts[r] * docs[(size_t)topi[r] * DD + j] / fmaxf(nrm5[r], EPSN);
        ctx[(size_t)b * DD + j] = c;
    }

    if (t < TOPK) {
        outp[b * TOPK + t] = topv[t];
        outp[BB * TOPK + b * TOPK + t] = (float)topi[t];
    }
}

// ---------------- K4b: ctxb[b][j] = ctx[b] . Wg[j, 512:1024] + bg[j] --------
__global__ __launch_bounds__(256) void k4b_ctxb_gemv(
    const float* __restrict__ ctx, const float* __restrict__ Wg,
    const float* __restrict__ bgt, float* __restrict__ ctxb) {
    int b = blockIdx.y, jc = blockIdx.x;
    int t = threadIdx.x;
    int r = t >> 4, c = t & 15;
    int row = jc * 16 + r;
    const float4* wr = (const float4*)(Wg + (size_t)row * (2 * DD) + DD);
    const float4* mv = (const float4*)(ctx + (size_t)b * DD);
    float acc = 0.f;
#pragma unroll
    for (int it = 0; it < 8; ++it) {
        int k4 = c + it * 16;
        float4 w = wr[k4], m = mv[k4];
        acc = fmaf(w.x, m.x, acc); acc = fmaf(w.y, m.y, acc);
        acc = fmaf(w.z, m.z, acc); acc = fmaf(w.w, m.w, acc);
    }
#pragma unroll
    for (int m = 1; m < 16; m <<= 1) acc += __shfl_xor(acc, m);
    if (c == 0) ctxb[(size_t)b * DD + row] = acc + bgt[row];
}

// ---------------- K5: bf16 MFMA gate GEMM + fused epilogue ----------------
#define BK 32
__global__ __launch_bounds__(512, 2) void k5_gemm_fused(
    const float* __restrict__ hs, const float* __restrict__ Wg,
    const float* __restrict__ ctx, const float* __restrict__ ctxb,
    float* __restrict__ outF) {
    __shared__ short At[128][BK];
    __shared__ short Bt[512][BK];
    __shared__ float ctxLds[DD];
    __shared__ float ctxbLds[DD];

    int bm = blockIdx.x;
    int t = threadIdx.x;
    int wv = t >> 6, lane = t & 63, ln = lane & 15, kg = lane >> 4;
    int wm = (wv >> 2) * 64, wn = (wv & 3) * 128;
    int bbatch = bm >> 4;

    ctxLds[t]  = ctx[(size_t)bbatch * DD + t];
    ctxbLds[t] = ctxb[(size_t)bbatch * DD + t];

    float4 pf[5][2];
    auto gload = [&](int kt) {
        {
            const float* src = hs + (size_t)(bm * 128 + (t >> 2)) * DD + kt * BK + (t & 3) * 8;
            pf[0][0] = ((const float4*)src)[0];
            pf[0][1] = ((const float4*)src)[1];
        }
#pragma unroll
        for (int i = 0; i < 4; ++i) {
            int u = t + i * 512;
            const float* src = Wg + (size_t)(u >> 2) * (2 * DD) + kt * BK + (u & 3) * 8;
            pf[1 + i][0] = ((const float4*)src)[0];
            pf[1 + i][1] = ((const float4*)src)[1];
        }
    };
    auto cvt1 = [&](float4 lo, float4 hi) {
        s16x8 cv;
        cv[0] = f2bf(lo.x); cv[1] = f2bf(lo.y); cv[2] = f2bf(lo.z); cv[3] = f2bf(lo.w);
        cv[4] = f2bf(hi.x); cv[5] = f2bf(hi.y); cv[6] = f2bf(hi.z); cv[7] = f2bf(hi.w);
        return cv;
    };
    auto cvtwrite = [&]() {
        {
            int row = t >> 2, slot = t & 3;
            int sl = slot ^ ((row >> 1) & 3);
            *(s16x8*)(&At[row][sl * 8]) = cvt1(pf[0][0], pf[0][1]);
        }
#pragma unroll
        for (int i = 0; i < 4; ++i) {
            int u = t + i * 512;
            int row = u >> 2, slot = u & 3;
            int sl = slot ^ ((row >> 1) & 3);
            *(s16x8*)(&Bt[row][sl * 8]) = cvt1(pf[1 + i][0], pf[1 + i][1]);
        }
    };

    f32x4 accv[4][8];
#pragma unroll
    for (int i = 0; i < 4; ++i)
#pragma unroll
        for (int j = 0; j < 8; ++j) accv[i][j] = (f32x4){0.f, 0.f, 0.f, 0.f};

    gload(0);
    for (int kt = 0; kt < DD / BK; ++kt) {
        __syncthreads();
        cvtwrite();
        if (kt + 1 < DD / BK) gload(kt + 1);
        __syncthreads();
        s16x8 af[4], bfr[8];
#pragma unroll
        for (int mi = 0; mi < 4; ++mi) {
            int row = wm + mi * 16 + ln;
            int sl = kg ^ ((row >> 1) & 3);
            af[mi] = *(const s16x8*)&At[row][sl * 8];
        }
#pragma unroll
        for (int nj = 0; nj < 8; ++nj) {
            int row = wn + nj * 16 + ln;
            int sl = kg ^ ((row >> 1) & 3);
            bfr[nj] = *(const s16x8*)&Bt[row][sl * 8];
        }
#pragma unroll
        for (int mi = 0; mi < 4; ++mi)
#pragma unroll
            for (int nj = 0; nj < 8; ++nj)
                accv[mi][nj] = __builtin_amdgcn_mfma_f32_16x16x32_bf16(
                    af[mi], bfr[nj], accv[mi][nj], 0, 0, 0);
    }

#pragma unroll
    for (int mi = 0; mi < 4; ++mi)
#pragma unroll
        for (int nj = 0; nj < 8; ++nj)
#pragma unroll
            for (int r = 0; r < 4; ++r) {
                int ri = wm + mi * 16 + kg * 4 + r;
                int ci = wn + nj * 16 + ln;
                size_t grow = (size_t)bm * 128 + ri;
                float logit = accv[mi][nj][r] + ctxbLds[ci];
                float g = __builtin_amdgcn_rcpf(1.0f + __expf(-logit));
                float h = hs[grow * DD + ci];
                float cx = ctxLds[ci];
                outF[grow * DD + ci] = g * h + (1.0f - g) * cx;
            }
}

// ---------------- launch ----------------
extern "C" void kernel_launch(void* const* d_in, const int* in_sizes, int n_in,
                              void* d_out, int out_size, void* d_ws, size_t ws_size,
                              hipStream_t stream) {
    const float* hs   = (const float*)d_in[0];
    const float* docs = (const float*)d_in[1];
    const float* Wq   = (const float*)d_in[2];
    const float* bq   = (const float*)d_in[3];
    const float* Wg   = (const float*)d_in[4];
    const float* bgt  = (const float*)d_in[5];
    float* outp = (float*)d_out;
    float* ws = (float*)d_ws;

    float* partial = ws;                               // 32*16*512
    float* mean    = partial + 32 * BB * DD;
    float* qtmp    = mean + BB * DD;
    float* qv      = qtmp + BB * DD;
    float* ctx     = qv + BB * DD;
    float* ctxb    = ctx + BB * DD;
    float* cand_s  = ctxb + BB * DD;                   // NW*16*5 = 245760
    int*   cand_i  = (int*)(cand_s + (size_t)NW * BB * TOPK);
    float* qphys   = (float*)(cand_i + (size_t)NW * BB * TOPK);  // 8192 floats

    k1_mean_partial<<<dim3(32, BB), 128, 0, stream>>>(hs, partial);
    k1b_mean_reduce<<<dim3(4, BB), 128, 0, stream>>>(partial, mean);
    k2a_q_gemv<<<dim3(32, BB), 256, 0, stream>>>(mean, Wq, bq, qtmp);
    k2b_q_norm<<<BB, 256, 0, stream>>>(qtmp, qv);
    k2c_qsplit<<<1, 512, 0, stream>>>(qv, qphys);
    k3_scores<<<NBLK3, 256, 0, stream>>>(docs, qphys, cand_s, cand_i);
    k4a_topk_ctx<<<BB, 256, 0, stream>>>(docs, cand_s, cand_i, ctx, outp);
    k4b_ctxb_gemv<<<dim3(32, BB), 256, 0, stream>>>(ctx, Wg, bgt, ctxb);
    k5_gemm_fused<<<256, 512, 0, stream>>>(hs, Wg, ctx, ctxb,
                                           outp + 2 * BB * TOPK);
}

// Round 7
// 355.114 us; speedup vs baseline: 2.4114x; 2.4114x over previous
//
#include <hip/hip_runtime.h>
#include <hip/hip_bf16.h>
#include <math.h>

#define BB 16
#define SS 2048
#define DD 512
#define NDOCS 200000
#define TOPK 5
#define EPSN 1e-12f
#define NEG_INF (-3.0e38f)

#define NT3 (NDOCS / 64)        // 3125 tiles of 64 docs (exact)
#define NB3 782                 // 782 blocks x 4 waves = 3128 waves >= 3125

typedef short s16x8 __attribute__((ext_vector_type(8)));
typedef float f32x4 __attribute__((ext_vector_type(4)));

__device__ __forceinline__ short f2bf(float f) {
    __bf16 b = (__bf16)f;
    short s;
    __builtin_memcpy(&s, &b, 2);
    return s;
}

__device__ __forceinline__ void gload_lds16(const void* g, void* l) {
    __builtin_amdgcn_global_load_lds(
        (const __attribute__((address_space(1))) void*)g,
        (__attribute__((address_space(3))) void*)l, 16, 0, 0);
}

// ---------------- K1: partial mean pool: partial[32][16][512] ----------------
__global__ __launch_bounds__(128) void k1_mean_partial(
    const float* __restrict__ hs, float* __restrict__ partial) {
    int b = blockIdx.y, sc = blockIdx.x;
    int t = threadIdx.x;
    const float4* src = (const float4*)(hs + (size_t)(b * SS + sc * 64) * DD);
    float4 acc = {0.f, 0.f, 0.f, 0.f};
    for (int s = 0; s < 64; ++s) {
        float4 v = src[(size_t)s * 128 + t];
        acc.x += v.x; acc.y += v.y; acc.z += v.z; acc.w += v.w;
    }
    ((float4*)partial)[(size_t)(sc * BB + b) * 128 + t] = acc;
}

// ---------------- K1b: reduce partials -> mean[16][512] ----------------
__global__ __launch_bounds__(128) void k1b_mean_reduce(
    const float* __restrict__ partial, float* __restrict__ mean) {
    int b = blockIdx.y, jc = blockIdx.x;
    int j = jc * 128 + threadIdx.x;
    float s = 0.f;
    for (int c = 0; c < 32; ++c) s += partial[(size_t)(c * BB + b) * DD + j];
    mean[(size_t)b * DD + j] = s * (1.0f / 2048.0f);
}

// ---------------- K2a: qtmp[b][j] = mean[b] . Wq[j] + bq[j] ----------------
__global__ __launch_bounds__(256) void k2a_q_gemv(
    const float* __restrict__ mean, const float* __restrict__ Wq,
    const float* __restrict__ bq, float* __restrict__ qtmp) {
    int b = blockIdx.y, jc = blockIdx.x;
    int t = threadIdx.x;
    int r = t >> 4, c = t & 15;
    int row = jc * 16 + r;
    const float4* wr = (const float4*)(Wq + (size_t)row * DD);
    const float4* mv = (const float4*)(mean + (size_t)b * DD);
    float acc = 0.f;
#pragma unroll
    for (int it = 0; it < 8; ++it) {
        int k4 = c + it * 16;
        float4 w = wr[k4], m = mv[k4];
        acc = fmaf(w.x, m.x, acc); acc = fmaf(w.y, m.y, acc);
        acc = fmaf(w.z, m.z, acc); acc = fmaf(w.w, m.w, acc);
    }
#pragma unroll
    for (int m = 1; m < 16; m <<= 1) acc += __shfl_xor(acc, m);
    if (c == 0) qtmp[(size_t)b * DD + row] = acc + bq[row];
}

// ---------------- K2b: l2-normalize qtmp -> qv ----------------
__global__ __launch_bounds__(256) void k2b_q_norm(
    const float* __restrict__ qtmp, float* __restrict__ qv) {
    int b = blockIdx.x, t = threadIdx.x;
    __shared__ float red[4];
    float a0 = qtmp[(size_t)b * DD + t];
    float a1 = qtmp[(size_t)b * DD + t + 256];
    float ss = a0 * a0 + a1 * a1;
#pragma unroll
    for (int m = 1; m < 64; m <<= 1) ss += __shfl_xor(ss, m);
    if ((t & 63) == 0) red[t >> 6] = ss;
    __syncthreads();
    float inv = 1.0f / fmaxf(sqrtf(red[0] + red[1] + red[2] + red[3]), EPSN);
    qv[(size_t)b * DD + t] = a0 * inv;
    qv[(size_t)b * DD + t + 256] = a1 * inv;
}

// ---------------- K3: doc-per-lane streaming scan ----------------
// 782 blocks x 256 thr (4 waves). Wave gw owns docs [gw*64, gw*64+64).
// Lane l streams row gw*64+l serially; q[16][512] broadcast from LDS.
// Natural VGPR demand ~90: acc 16 + nrm + cur/nxt 32 + temps. No forced cap.
__global__ __launch_bounds__(256, 1) void k3_scores(
    const float* __restrict__ docs, const float* __restrict__ qv,
    float* __restrict__ cand_s, int* __restrict__ cand_i) {
    __shared__ float qS[BB * DD];   // 32KB, [b][k] == qv layout verbatim

    int t = threadIdx.x;
    int w = t >> 6, lane = t & 63;

    // stage q table once (linear copy, 2048 float4 units over 256 threads)
#pragma unroll
    for (int jj = 0; jj < 8; ++jj) {
        int u = ((w * 8 + jj) << 6) + lane;
        gload_lds16(qv + (size_t)u * 4, (void*)&qS[(w * 8 + jj) * 256]);
    }
    __syncthreads();

    int gw = blockIdx.x * 4 + w;
    if (gw >= NT3) return;

    const float4* dp = (const float4*)(docs + (size_t)(gw * 64 + lane) * DD);
    const float4* q4 = (const float4*)qS;    // [b*128 + k4], uniform broadcast

    float acc[BB];
#pragma unroll
    for (int b = 0; b < BB; ++b) acc[b] = 0.f;
    float nrm = 0.f;

    float4 cur[4], nxt[4];
#pragma unroll
    for (int i = 0; i < 4; ++i) cur[i] = dp[i];

    for (int g = 0; g < 32; ++g) {               // 16 dims per iteration
        int gn = (g < 31) ? (g + 1) : 31;        // last iter reloads (harmless)
#pragma unroll
        for (int i = 0; i < 4; ++i) nxt[i] = dp[gn * 4 + i];
#pragma unroll
        for (int i = 0; i < 4; ++i) {
            float4 e = cur[i];
            int k4 = g * 4 + i;
            nrm = fmaf(e.x, e.x, fmaf(e.y, e.y, fmaf(e.z, e.z, fmaf(e.w, e.w, nrm))));
#pragma unroll
            for (int b = 0; b < BB; ++b) {
                float4 qq = q4[b * 128 + k4];    // ds_read_b128, imm offset b*2048
                acc[b] = fmaf(e.x, qq.x, fmaf(e.y, qq.y,
                          fmaf(e.z, qq.z, fmaf(e.w, qq.w, acc[b]))));
            }
        }
#pragma unroll
        for (int i = 0; i < 4; ++i) cur[i] = nxt[i];
    }

    float invn = 1.0f / fmaxf(sqrtf(nrm), EPSN);
    long base = (long)gw * 64;

    // per-batch top-5 of the wave's 64 docs: 5-round butterfly argmax
#pragma unroll 1
    for (int b = 0; b < BB; ++b) {
        float v = acc[b] * invn;
        float lvv[TOPK]; int lii[TOPK];
#pragma unroll
        for (int r = 0; r < TOPK; ++r) {
            float bv = v; int bi = lane;
#pragma unroll
            for (int mm = 1; mm < 64; mm <<= 1) {
                float ov = __shfl_xor(bv, mm);
                int   oi = __shfl_xor(bi, mm);
                if (ov > bv || (ov == bv && oi < bi)) { bv = ov; bi = oi; }
            }
            lvv[r] = bv; lii[r] = bi;
            if (lane == bi) v = NEG_INF;         // mask winner, next round
        }
        if (lane == 0) {
#pragma unroll
            for (int r = 0; r < TOPK; ++r) {
                cand_s[((long)gw * BB + b) * TOPK + r] = lvv[r];
                cand_i[((long)gw * BB + b) * TOPK + r] = (int)(base + lii[r]);
            }
        }
    }
}

// ---------------- K4a: merge top-5, softmax, context, outputs ----------------
__global__ __launch_bounds__(256) void k4a_topk_ctx(
    const float* __restrict__ docs, const float* __restrict__ cand_s,
    const int* __restrict__ cand_i, float* __restrict__ ctx,
    float* __restrict__ outp) {
    int b = blockIdx.x, t = threadIdx.x;
    __shared__ float sv[256];
    __shared__ int   si[256];
    __shared__ float topv[TOPK];
    __shared__ int   topi[TOPK];
    __shared__ float red[4];
    __shared__ float nrm5[TOPK];
    __shared__ float wts[TOPK];

    float lv[TOPK]; int li[TOPK];
#pragma unroll
    for (int r = 0; r < TOPK; ++r) { lv[r] = NEG_INF; li[r] = 0x7fffffff; }

    for (int j = t; j < NT3 * TOPK; j += 256) {
        int blk = j / TOPK, r = j - blk * TOPK;
        float s = cand_s[(long)blk * (BB * TOPK) + b * TOPK + r];
        int  di = cand_i[(long)blk * (BB * TOPK) + b * TOPK + r];
        if (s > lv[TOPK - 1] || (s == lv[TOPK - 1] && di < li[TOPK - 1])) {
            lv[TOPK - 1] = s; li[TOPK - 1] = di;
#pragma unroll
            for (int k = TOPK - 1; k > 0; --k) {
                if (lv[k] > lv[k - 1] || (lv[k] == lv[k - 1] && li[k] < li[k - 1])) {
                    float tv = lv[k]; lv[k] = lv[k - 1]; lv[k - 1] = tv;
                    int   ti = li[k]; li[k] = li[k - 1]; li[k - 1] = ti;
                }
            }
        }
    }

    int p = 0;
    for (int r = 0; r < TOPK; ++r) {
        float hv = (p < TOPK) ? lv[p] : NEG_INF;
        int   hi = (p < TOPK) ? li[p] : 0x7fffffff;
        sv[t] = hv; si[t] = hi;
        __syncthreads();
        for (int off = 128; off > 0; off >>= 1) {
            if (t < off) {
                float ov = sv[t + off]; int oi = si[t + off];
                if (ov > sv[t] || (ov == sv[t] && oi < si[t])) { sv[t] = ov; si[t] = oi; }
            }
            __syncthreads();
        }
        if (t == 0) { topv[r] = sv[0]; topi[r] = si[0]; }
        __syncthreads();
        if (hv == topv[r] && hi == topi[r]) ++p;
        __syncthreads();
    }

    for (int r = 0; r < TOPK; ++r) {
        const float* dr = docs + (size_t)topi[r] * DD;
        float s2 = dr[t] * dr[t] + dr[t + 256] * dr[t + 256];
#pragma unroll
        for (int m = 1; m < 64; m <<= 1) s2 += __shfl_xor(s2, m);
        if ((t & 63) == 0) red[t >> 6] = s2;
        __syncthreads();
        if (t == 0) nrm5[r] = sqrtf(red[0] + red[1] + red[2] + red[3]);
        __syncthreads();
    }

    if (t == 0) {
        float m = topv[0];
        float e[TOPK], s = 0.f;
#pragma unroll
        for (int r = 0; r < TOPK; ++r) { e[r] = expf(topv[r] - m); s += e[r]; }
#pragma unroll
        for (int r = 0; r < TOPK; ++r) wts[r] = e[r] / s;
    }
    __syncthreads();

    for (int j = t; j < DD; j += 256) {
        float c = 0.f;
#pragma unroll
        for (int r = 0; r < TOPK; ++r)
            c += wts[r] * docs[(size_t)topi[r] * DD + j] / fmaxf(nrm5[r], EPSN);
        ctx[(size_t)b * DD + j] = c;
    }

    if (t < TOPK) {
        outp[b * TOPK + t] = topv[t];
        outp[BB * TOPK + b * TOPK + t] = (float)topi[t];
    }
}

// ---------------- K4b: ctxb[b][j] = ctx[b] . Wg[j, 512:1024] + bg[j] --------
__global__ __launch_bounds__(256) void k4b_ctxb_gemv(
    const float* __restrict__ ctx, const float* __restrict__ Wg,
    const float* __restrict__ bgt, float* __restrict__ ctxb) {
    int b = blockIdx.y, jc = blockIdx.x;
    int t = threadIdx.x;
    int r = t >> 4, c = t & 15;
    int row = jc * 16 + r;
    const float4* wr = (const float4*)(Wg + (size_t)row * (2 * DD) + DD);
    const float4* mv = (const float4*)(ctx + (size_t)b * DD);
    float acc = 0.f;
#pragma unroll
    for (int it = 0; it < 8; ++it) {
        int k4 = c + it * 16;
        float4 w = wr[k4], m = mv[k4];
        acc = fmaf(w.x, m.x, acc); acc = fmaf(w.y, m.y, acc);
        acc = fmaf(w.z, m.z, acc); acc = fmaf(w.w, m.w, acc);
    }
#pragma unroll
    for (int m = 1; m < 16; m <<= 1) acc += __shfl_xor(acc, m);
    if (c == 0) ctxb[(size_t)b * DD + row] = acc + bgt[row];
}

// ---------------- K5: bf16 MFMA gate GEMM + fused epilogue ----------------
#define BK 32
__global__ __launch_bounds__(512, 2) void k5_gemm_fused(
    const float* __restrict__ hs, const float* __restrict__ Wg,
    const float* __restrict__ ctx, const float* __restrict__ ctxb,
    float* __restrict__ outF) {
    __shared__ short At[128][BK];
    __shared__ short Bt[512][BK];
    __shared__ float ctxLds[DD];
    __shared__ float ctxbLds[DD];

    int bm = blockIdx.x;
    int t = threadIdx.x;
    int wv = t >> 6, lane = t & 63, ln = lane & 15, kg = lane >> 4;
    int wm = (wv >> 2) * 64, wn = (wv & 3) * 128;
    int bbatch = bm >> 4;

    ctxLds[t]  = ctx[(size_t)bbatch * DD + t];
    ctxbLds[t] = ctxb[(size_t)bbatch * DD + t];

    float4 pf[5][2];
    auto gload = [&](int kt) {
        {
            const float* src = hs + (size_t)(bm * 128 + (t >> 2)) * DD + kt * BK + (t & 3) * 8;
            pf[0][0] = ((const float4*)src)[0];
            pf[0][1] = ((const float4*)src)[1];
        }
#pragma unroll
        for (int i = 0; i < 4; ++i) {
            int u = t + i * 512;
            const float* src = Wg + (size_t)(u >> 2) * (2 * DD) + kt * BK + (u & 3) * 8;
            pf[1 + i][0] = ((const float4*)src)[0];
            pf[1 + i][1] = ((const float4*)src)[1];
        }
    };
    auto cvt1 = [&](float4 lo, float4 hi) {
        s16x8 cv;
        cv[0] = f2bf(lo.x); cv[1] = f2bf(lo.y); cv[2] = f2bf(lo.z); cv[3] = f2bf(lo.w);
        cv[4] = f2bf(hi.x); cv[5] = f2bf(hi.y); cv[6] = f2bf(hi.z); cv[7] = f2bf(hi.w);
        return cv;
    };
    auto cvtwrite = [&]() {
        {
            int row = t >> 2, slot = t & 3;
            int sl = slot ^ ((row >> 1) & 3);
            *(s16x8*)(&At[row][sl * 8]) = cvt1(pf[0][0], pf[0][1]);
        }
#pragma unroll
        for (int i = 0; i < 4; ++i) {
            int u = t + i * 512;
            int row = u >> 2, slot = u & 3;
            int sl = slot ^ ((row >> 1) & 3);
            *(s16x8*)(&Bt[row][sl * 8]) = cvt1(pf[1 + i][0], pf[1 + i][1]);
        }
    };

    f32x4 accv[4][8];
#pragma unroll
    for (int i = 0; i < 4; ++i)
#pragma unroll
        for (int j = 0; j < 8; ++j) accv[i][j] = (f32x4){0.f, 0.f, 0.f, 0.f};

    gload(0);
    for (int kt = 0; kt < DD / BK; ++kt) {
        __syncthreads();
        cvtwrite();
        if (kt + 1 < DD / BK) gload(kt + 1);
        __syncthreads();
        s16x8 af[4], bfr[8];
#pragma unroll
        for (int mi = 0; mi < 4; ++mi) {
            int row = wm + mi * 16 + ln;
            int sl = kg ^ ((row >> 1) & 3);
            af[mi] = *(const s16x8*)&At[row][sl * 8];
        }
#pragma unroll
        for (int nj = 0; nj < 8; ++nj) {
            int row = wn + nj * 16 + ln;
            int sl = kg ^ ((row >> 1) & 3);
            bfr[nj] = *(const s16x8*)&Bt[row][sl * 8];
        }
#pragma unroll
        for (int mi = 0; mi < 4; ++mi)
#pragma unroll
            for (int nj = 0; nj < 8; ++nj)
                accv[mi][nj] = __builtin_amdgcn_mfma_f32_16x16x32_bf16(
                    af[mi], bfr[nj], accv[mi][nj], 0, 0, 0);
    }

#pragma unroll
    for (int mi = 0; mi < 4; ++mi)
#pragma unroll
        for (int nj = 0; nj < 8; ++nj)
#pragma unroll
            for (int r = 0; r < 4; ++r) {
                int ri = wm + mi * 16 + kg * 4 + r;
                int ci = wn + nj * 16 + ln;
                size_t grow = (size_t)bm * 128 + ri;
                float logit = accv[mi][nj][r] + ctxbLds[ci];
                float g = __builtin_amdgcn_rcpf(1.0f + __expf(-logit));
                float h = hs[grow * DD + ci];
                float cx = ctxLds[ci];
                outF[grow * DD + ci] = g * h + (1.0f - g) * cx;
            }
}

// ---------------- launch ----------------
extern "C" void kernel_launch(void* const* d_in, const int* in_sizes, int n_in,
                              void* d_out, int out_size, void* d_ws, size_t ws_size,
                              hipStream_t stream) {
    const float* hs   = (const float*)d_in[0];
    const float* docs = (const float*)d_in[1];
    const float* Wq   = (const float*)d_in[2];
    const float* bq   = (const float*)d_in[3];
    const float* Wg   = (const float*)d_in[4];
    const float* bgt  = (const float*)d_in[5];
    float* outp = (float*)d_out;
    float* ws = (float*)d_ws;

    float* partial = ws;                               // 32*16*512
    float* mean    = partial + 32 * BB * DD;
    float* qtmp    = mean + BB * DD;
    float* qv      = qtmp + BB * DD;
    float* ctx     = qv + BB * DD;
    float* ctxb    = ctx + BB * DD;
    float* cand_s  = ctxb + BB * DD;                   // NT3*16*5 = 250000
    int*   cand_i  = (int*)(cand_s + (size_t)NT3 * BB * TOPK);

    k1_mean_partial<<<dim3(32, BB), 128, 0, stream>>>(hs, partial);
    k1b_mean_reduce<<<dim3(4, BB), 128, 0, stream>>>(partial, mean);
    k2a_q_gemv<<<dim3(32, BB), 256, 0, stream>>>(mean, Wq, bq, qtmp);
    k2b_q_norm<<<BB, 256, 0, stream>>>(qtmp, qv);
    k3_scores<<<NB3, 256, 0, stream>>>(docs, qv, cand_s, cand_i);
    k4a_topk_ctx<<<BB, 256, 0, stream>>>(docs, cand_s, cand_i, ctx, outp);
    k4b_ctxb_gemv<<<dim3(32, BB), 256, 0, stream>>>(ctx, Wg, bgt, ctxb);
    k5_gemm_fused<<<256, 512, 0, stream>>>(hs, Wg, ctx, ctxb,
                                           outp + 2 * BB * TOPK);
}